// Round 3
// baseline (48.540 us; speedup 1.0000x reference)
//
#include <hip/hip_runtime.h>

#define QK4   20000      // 80000 floats / 4 per float4, per batch
#define K_TOP 300
#define NCLS  80
#define NCAND 2048
#define NBUCK 4096

__device__ __forceinline__ unsigned int order_f32(float f) {
    unsigned int u = __float_as_uint(f);
    return u ^ ((u >> 31) ? 0xFFFFFFFFu : 0x80000000u);
}
__device__ __forceinline__ float unorder_f32(unsigned int u) {
    unsigned int v = (u & 0x80000000u) ? (u ^ 0x80000000u) : ~u;
    return __uint_as_float(v);
}

#define HIST4(v)                                      \
    do {                                              \
        atomicAdd(&hist[order_f32((v).x) >> 20], 1u); \
        atomicAdd(&hist[order_f32((v).y) >> 20], 1u); \
        atomicAdd(&hist[order_f32((v).z) >> 20], 1u); \
        atomicAdd(&hist[order_f32((v).w) >> 20], 1u); \
    } while (0)

__device__ __forceinline__ void collect1(float v, int idx, unsigned int B,
                                         unsigned long long* cand,
                                         unsigned int* cur) {
    unsigned int o  = order_f32(v);
    unsigned int bk = o >> 20;
    if (bk >= B) {
        unsigned int pos = atomicAdd(&cur[bk], 1u);
        if (pos < NCAND)
            cand[pos] = ((unsigned long long)o << 32) |
                        (unsigned long long)(0xFFFFFFFFu - (unsigned int)idx);
    }
}

#define COLL4(v, base)                                 \
    do {                                               \
        collect1((v).x, (base) + 0, B, cand, cur);     \
        collect1((v).y, (base) + 1, B, cand, cur);     \
        collect1((v).z, (base) + 2, B, cand, cur);     \
        collect1((v).w, (base) + 3, B, cand, cur);     \
    } while (0)

__device__ __forceinline__ void write_row(float* __restrict__ out, int b, int rank,
                                          unsigned long long key,
                                          const float4* __restrict__ BX,
                                          float sx, float sy) {
    unsigned int o   = (unsigned int)(key >> 32);
    unsigned int idx = ~((unsigned int)key);
    float logit = unorder_f32(o);
    float score = 1.0f / (1.0f + expf(-logit));
    int label = (int)(idx % NCLS);
    int q     = (int)(idx / NCLS);
    float4 bx = BX[q];
    float* po = out + ((size_t)b * K_TOP + rank) * 6;
    po[0] = (float)label;
    po[1] = score;
    po[2] = (bx.x - 0.5f * bx.z) * sx;
    po[3] = (bx.y - 0.5f * bx.w) * sy;
    po[4] = bx.z * sx;
    po[5] = bx.w * sy;
}

__global__ __launch_bounds__(1024) void detr_post_kernel(
    const float* __restrict__ logits,
    const float* __restrict__ boxes,
    const int*   __restrict__ osz,
    float*       __restrict__ out)
{
    __shared__ unsigned int       hist[NBUCK];  // counts -> segment starts
    __shared__ unsigned int       cur[NBUCK];   // fill cursors (end after pass 2)
    __shared__ unsigned long long cand[NCAND];  // bucket-grouped candidates
    __shared__ unsigned int       csum[1024];
    __shared__ unsigned int       csum2[64];
    __shared__ int s_B;

    const int b = blockIdx.x;
    const int t = threadIdx.x;
    const float4* L4 = (const float4*)(logits + (size_t)b * (QK4 * 4));

    for (int i = t; i < NBUCK; i += 1024) hist[i] = 0;
    if (t == 0) s_B = -1;
    __syncthreads();

    // ---- pass 1: 12-bit histogram of ordered float bits; 8 loads in flight ----
    {
        int i = t;
        #pragma unroll
        for (int c = 0; c < 2; ++c, i += 8192) {
            float4 a0 = L4[i];
            float4 a1 = L4[i + 1024];
            float4 a2 = L4[i + 2048];
            float4 a3 = L4[i + 3072];
            float4 a4 = L4[i + 4096];
            float4 a5 = L4[i + 5120];
            float4 a6 = L4[i + 6144];
            float4 a7 = L4[i + 7168];
            HIST4(a0); HIST4(a1); HIST4(a2); HIST4(a3);
            HIST4(a4); HIST4(a5); HIST4(a6); HIST4(a7);
        }
        // i == t + 16384; rounds 16..18 always valid, round 19 for t < 544
        float4 a0 = L4[i];
        float4 a1 = L4[i + 1024];
        float4 a2 = L4[i + 2048];
        float4 a3;
        const bool tail = (t < 544);
        if (tail) a3 = L4[19456 + t];
        HIST4(a0); HIST4(a1); HIST4(a2);
        if (tail) HIST4(a3);
    }
    __syncthreads();

    // ---- suffix-scan: hist[bk] -> start[bk] = #keys in buckets > bk,
    //      and find B = max bk with start[bk] + cnt[bk] >= K_TOP ----
    csum[t] = hist[4*t] + hist[4*t+1] + hist[4*t+2] + hist[4*t+3];
    __syncthreads();
    if (t < 64) {
        unsigned int s = 0;
        for (int u = 0; u < 16; ++u) s += csum[16*t + u];
        csum2[t] = s;
    }
    __syncthreads();
    if (t == 0) {     // exclusive suffix over the 64 supergroup sums
        unsigned int run = 0;
        for (int s = 63; s >= 0; --s) { unsigned int v = csum2[s]; csum2[s] = run; run += v; }
    }
    __syncthreads();
    {
        // exclusive suffix down to this thread's group of 4 buckets
        unsigned int ex = csum2[t >> 4];
        for (int g2 = (t | 15); g2 > t; --g2) ex += csum[g2];
        unsigned int h0 = hist[4*t], h1 = hist[4*t+1], h2 = hist[4*t+2], h3 = hist[4*t+3];
        unsigned int st3 = ex;
        unsigned int st2 = st3 + h3;
        unsigned int st1 = st2 + h2;
        unsigned int st0 = st1 + h1;
        int bl = -1;   // suffix(>=bk) non-increasing in bk: first hit from top is max
        if      (st3 + h3 >= K_TOP) bl = 4*t + 3;
        else if (st2 + h2 >= K_TOP) bl = 4*t + 2;
        else if (st1 + h1 >= K_TOP) bl = 4*t + 1;
        else if (st0 + h0 >= K_TOP) bl = 4*t + 0;
        if (bl >= 0) atomicMax(&s_B, bl);
        hist[4*t] = st0; hist[4*t+1] = st1; hist[4*t+2] = st2; hist[4*t+3] = st3;
        cur [4*t] = st0; cur [4*t+1] = st1; cur [4*t+2] = st2; cur [4*t+3] = st3;
    }
    __syncthreads();
    const unsigned int B = (unsigned int)s_B;

    // ---- pass 2 (cache-resident): collect bucket-grouped candidates ----
    {
        int i = t;
        #pragma unroll
        for (int c = 0; c < 2; ++c, i += 8192) {
            float4 a0 = L4[i];
            float4 a1 = L4[i + 1024];
            float4 a2 = L4[i + 2048];
            float4 a3 = L4[i + 3072];
            float4 a4 = L4[i + 4096];
            float4 a5 = L4[i + 5120];
            float4 a6 = L4[i + 6144];
            float4 a7 = L4[i + 7168];
            COLL4(a0, 4*i);          COLL4(a1, 4*(i+1024));
            COLL4(a2, 4*(i+2048));   COLL4(a3, 4*(i+3072));
            COLL4(a4, 4*(i+4096));   COLL4(a5, 4*(i+5120));
            COLL4(a6, 4*(i+6144));   COLL4(a7, 4*(i+7168));
        }
        float4 a0 = L4[i];
        float4 a1 = L4[i + 1024];
        float4 a2 = L4[i + 2048];
        float4 a3;
        const bool tail = (t < 544);
        if (tail) a3 = L4[19456 + t];
        COLL4(a0, 4*i); COLL4(a1, 4*(i+1024)); COLL4(a2, 4*(i+2048));
        if (tail) COLL4(a3, 4*(19456 + t));
    }
    __syncthreads();

    // ---- rank within own bucket segment only; write top-300 ----
    const float sx = (float)osz[1];   // scale = [W, H, W, H]
    const float sy = (float)osz[0];
    const float4* BX = (const float4*)(boxes + (size_t)b * 4000);

    int total = (int)cur[B]; if (total > NCAND) total = NCAND;
    for (int i = t; i < total; i += 1024) {
        unsigned long long key = cand[i];
        int bk   = (int)(key >> 52);
        int segS = (int)hist[bk];
        int segE = (int)cur[bk]; if (segE > NCAND) segE = NCAND;
        int r = segS;
        for (int j = segS; j < segE; ++j)
            r += (cand[j] > key) ? 1 : 0;
        if (r < K_TOP)
            write_row(out, b, r, key, BX, sx, sy);
    }
}

extern "C" void kernel_launch(void* const* d_in, const int* in_sizes, int n_in,
                              void* d_out, int out_size, void* d_ws, size_t ws_size,
                              hipStream_t stream) {
    const float* logits = (const float*)d_in[0];
    const float* boxes  = (const float*)d_in[1];
    const int*   osz    = (const int*)d_in[2];
    float* out = (float*)d_out;
    detr_post_kernel<<<dim3(256), dim3(1024), 0, stream>>>(logits, boxes, osz, out);
}